// Round 1
// baseline (348.427 us; speedup 1.0000x reference)
//
#include <hip/hip_runtime.h>
#include <math.h>

// GATConv (PyG 1.3.2 semantics), H=1, IN=C=128, fp32 throughout.
// Pipeline: zero -> gemm(h=xW) -> dots(ad/as) -> count -> scan -> fill(CSR) -> aggregate.

constexpr int CH = 128;

__global__ __launch_bounds__(256) void zero_kernel(int* __restrict__ p, int n) {
    int i = blockIdx.x * blockDim.x + threadIdx.x;
    if (i < n) p[i] = 0;
}

// h[n][c] = sum_k x[n][k] * W[k][c].  BM=64 rows/block, all 128 cols.
// W (64KB) staged in LDS; x read via broadcast global loads (L1-resident rows).
// thread: rg=tid>>5 (8 rows), cg=tid&31 (4 cols) -> 32 accumulators.
__global__ __launch_bounds__(256) void gemm_kernel(const float* __restrict__ x,
                                                   const float* __restrict__ W,
                                                   float* __restrict__ h, int n) {
    __shared__ float Ws[CH * CH];   // 64 KB
    const int tid = threadIdx.x;
    {
        const float4* Wv = (const float4*)W;
        float4* Wsv = (float4*)Ws;
        #pragma unroll
        for (int i = 0; i < 16; ++i)
            Wsv[tid + i * 256] = Wv[tid + i * 256];
    }
    __syncthreads();
    const int rg = tid >> 5;
    const int c0 = (tid & 31) * 4;
    const int row0 = blockIdx.x * 64 + rg * 8;
    int r[8];
    #pragma unroll
    for (int i = 0; i < 8; ++i) r[i] = min(row0 + i, n - 1);  // clamp (guarded store)
    float acc[8][4] = {};
    #pragma unroll 8
    for (int k = 0; k < CH; ++k) {
        const float4 wb = *(const float4*)&Ws[k * CH + c0];
        #pragma unroll
        for (int i = 0; i < 8; ++i) {
            const float xa = x[r[i] * CH + k];   // broadcast within half-wave
            acc[i][0] = fmaf(xa, wb.x, acc[i][0]);
            acc[i][1] = fmaf(xa, wb.y, acc[i][1]);
            acc[i][2] = fmaf(xa, wb.z, acc[i][2]);
            acc[i][3] = fmaf(xa, wb.w, acc[i][3]);
        }
    }
    #pragma unroll
    for (int i = 0; i < 8; ++i) {
        const int row = row0 + i;
        if (row < n) {
            float4 o = make_float4(acc[i][0], acc[i][1], acc[i][2], acc[i][3]);
            *(float4*)&h[row * CH + c0] = o;
        }
    }
}

// ad[n] = h[n] . att[0:128]   (x_i / dst half)
// as[n] = h[n] . att[128:256] (x_j / src half)
__global__ __launch_bounds__(256) void dots_kernel(const float* __restrict__ h,
                                                   const float* __restrict__ att,
                                                   float* __restrict__ ad,
                                                   float* __restrict__ as_, int n) {
    const int w = (int)((blockIdx.x * blockDim.x + threadIdx.x) >> 6);
    if (w >= n) return;
    const int lane = threadIdx.x & 63;
    const float h0 = h[w * CH + lane];
    const float h1 = h[w * CH + 64 + lane];
    float d = h0 * att[lane] + h1 * att[64 + lane];
    float s = h0 * att[128 + lane] + h1 * att[192 + lane];
    #pragma unroll
    for (int off = 32; off >= 1; off >>= 1) {
        d += __shfl_xor(d, off, 64);
        s += __shfl_xor(s, off, 64);
    }
    if (lane == 0) { ad[w] = d; as_[w] = s; }
}

__global__ __launch_bounds__(256) void count_kernel(const int* __restrict__ dst,
                                                    int* __restrict__ counts, int etot) {
    int e = blockIdx.x * blockDim.x + threadIdx.x;
    if (e < etot) atomicAdd(&counts[dst[e]], 1);
}

// exclusive prefix sum of counts -> offsets[0..n], single block of 1024.
__global__ __launch_bounds__(1024) void scan_kernel(const int* __restrict__ counts,
                                                    int* __restrict__ offsets, int n) {
    __shared__ int wsums[16];
    __shared__ int chunk_base;
    const int tid = threadIdx.x;
    const int lane = tid & 63, wid = tid >> 6;
    if (tid == 0) { chunk_base = 0; offsets[0] = 0; }
    __syncthreads();
    for (int base = 0; base < n; base += 1024) {
        const int i = base + tid;
        int v = (i < n) ? counts[i] : 0;
        // inclusive wave scan
        #pragma unroll
        for (int off = 1; off < 64; off <<= 1) {
            int t = __shfl_up(v, (unsigned)off, 64);
            if (lane >= off) v += t;
        }
        if (lane == 63) wsums[wid] = v;
        __syncthreads();
        if (wid == 0) {
            int s = (lane < 16) ? wsums[lane] : 0;
            #pragma unroll
            for (int off = 1; off < 16; off <<= 1) {
                int t = __shfl_up(s, (unsigned)off, 64);
                if (lane >= off) s += t;
            }
            if (lane < 16) wsums[lane] = s;   // inclusive wave sums
        }
        __syncthreads();
        const int wave_excl = (wid == 0) ? 0 : wsums[wid - 1];
        const int incl = chunk_base + wave_excl + v;
        if (i < n) offsets[i + 1] = incl;
        __syncthreads();
        if (tid == 1023) chunk_base = incl;   // chunk total
        __syncthreads();
    }
}

__global__ __launch_bounds__(256) void fill_kernel(const int* __restrict__ src,
                                                   const int* __restrict__ dst,
                                                   const int* __restrict__ offsets,
                                                   int* __restrict__ cursor,
                                                   int* __restrict__ srcs_sorted, int etot) {
    int e = blockIdx.x * blockDim.x + threadIdx.x;
    if (e < etot) {
        const int d = dst[e];
        const int p = atomicAdd(&cursor[d], 1);
        srcs_sorted[offsets[d] + p] = src[e];
    }
}

// One wave per destination node: two-pass segment softmax + weighted gather.
__global__ __launch_bounds__(256) void aggregate_kernel(const float* __restrict__ h,
                                                        const float* __restrict__ ad,
                                                        const float* __restrict__ as_,
                                                        const int* __restrict__ offsets,
                                                        const int* __restrict__ srcs,
                                                        const float* __restrict__ bias,
                                                        float* __restrict__ out, int n) {
    const int node = (int)((blockIdx.x * blockDim.x + threadIdx.x) >> 6);
    if (node >= n) return;
    const int lane = threadIdx.x & 63;
    const int start = offsets[node];
    const int end = offsets[node + 1];
    const float adn = ad[node];

    // phase A: segment max of leaky_relu(ad[n] + as[src]) — lane-parallel
    float m = -INFINITY;
    for (int e = start + lane; e < end; e += 64) {
        float a = adn + as_[srcs[e]];
        a = (a >= 0.f) ? a : 0.2f * a;
        m = fmaxf(m, a);
    }
    #pragma unroll
    for (int off = 32; off >= 1; off >>= 1)
        m = fmaxf(m, __shfl_xor(m, off, 64));

    // phase B: serial over edges, all lanes compute p redundantly; 2 ch/lane
    float ssum = 0.f, acc0 = 0.f, acc1 = 0.f;
    for (int e = start; e < end; ++e) {
        const int sc = srcs[e];                 // broadcast load
        float a = adn + as_[sc];                // broadcast load
        a = (a >= 0.f) ? a : 0.2f * a;
        const float p = __expf(a - m);
        ssum += p;
        const float2 hv = *(const float2*)&h[sc * CH + lane * 2];  // coalesced 512B
        acc0 = fmaf(p, hv.x, acc0);
        acc1 = fmaf(p, hv.y, acc1);
    }
    const float inv = 1.f / (ssum + 1e-16f);
    const float2 bv = *(const float2*)&bias[lane * 2];
    float2 o;
    o.x = fmaf(acc0, inv, bv.x);
    o.y = fmaf(acc1, inv, bv.y);
    *(float2*)&out[node * CH + lane * 2] = o;
}

extern "C" void kernel_launch(void* const* d_in, const int* in_sizes, int n_in,
                              void* d_out, int out_size, void* d_ws, size_t ws_size,
                              hipStream_t stream) {
    const float* x    = (const float*)d_in[0];
    const int*   ei   = (const int*)d_in[1];
    const float* W    = (const float*)d_in[2];
    const float* att  = (const float*)d_in[3];
    const float* bias = (const float*)d_in[4];
    float* out = (float*)d_out;

    const int N_   = in_sizes[0] / CH;   // 50000
    const int Etot = in_sizes[1] / 2;    // 850000
    const int* src = ei;
    const int* dst = ei + Etot;

    // workspace carve-up (all 256B-aligned); total ~30 MB
    char* ws = (char*)d_ws;
    size_t off = 0;
    auto alloc = [&](size_t bytes) -> void* {
        void* p = ws + off;
        off = (off + bytes + 255) & ~(size_t)255;
        return p;
    };
    float* h        = (float*)alloc((size_t)N_ * CH * sizeof(float));
    float* ad       = (float*)alloc((size_t)N_ * sizeof(float));
    float* as_      = (float*)alloc((size_t)N_ * sizeof(float));
    int*   counts   = (int*)  alloc((size_t)2 * N_ * sizeof(int));  // counts + cursor
    int*   cursor   = counts + N_;
    int*   offsets  = (int*)  alloc((size_t)(N_ + 1) * sizeof(int));
    int*   srcs_srt = (int*)  alloc((size_t)Etot * sizeof(int));
    (void)ws_size; (void)n_in; (void)out_size;

    zero_kernel<<<(2 * N_ + 255) / 256, 256, 0, stream>>>(counts, 2 * N_);
    gemm_kernel<<<(N_ + 63) / 64, 256, 0, stream>>>(x, W, h, N_);
    dots_kernel<<<(N_ + 3) / 4, 256, 0, stream>>>(h, att, ad, as_, N_);
    count_kernel<<<(Etot + 255) / 256, 256, 0, stream>>>(dst, counts, Etot);
    scan_kernel<<<1, 1024, 0, stream>>>(counts, offsets, N_);
    fill_kernel<<<(Etot + 255) / 256, 256, 0, stream>>>(src, dst, offsets, cursor, srcs_srt, Etot);
    aggregate_kernel<<<(N_ + 3) / 4, 256, 0, stream>>>(h, ad, as_, offsets, srcs_srt, bias, out, N_);
}